// Round 14
// baseline (1463.586 us; speedup 1.0000x reference)
//
#include <hip/hip_runtime.h>

// CAGenerator: 64-step neural CA — 2 dispatches/step, fence-free.
// R14 = R13 + k1 restructure: 512-thread blocks, grid (32 bands x 8 chunks)
// = 256 blocks x 8 waves = 16 waves/CU (2x R13) for L2-latency hiding, with
// 8-row bands halving per-step weight traffic (47 -> 23.6 MB) and staging
// duplication (16.7 -> 13.9 MB). Staging is two-phase (hoisted loads ->
// LDS stores). Per-wave inner loop identical to R13 (90 MFMA, depth-8 ring).
// Structure: k1 computes H = relu(Wc*im2col(S)) and accumulates the alpha
// dot into Aseed (65K coalesced atomics/step); k2 does upd = W3*H for its
// own row, live mask from Aseed/Sold, state write (Sf32 + Smf16), and seeds
// the next step's Aseed.
// Folded: Wc = W2@W1 (512x720), bc = W2@b1+b2. mask=uniform()<1.0 -> no RNG.
// K-permutation kp = tap*80+ci: B-fragment = one ds_read_b128 from msT.

#define NPIX 8192
#define T_ALIVE 0.01f

typedef _Float16 f16;
typedef __attribute__((ext_vector_type(8)))  _Float16 h8_t;
typedef __attribute__((ext_vector_type(4)))  _Float16 h4_t;
typedef __attribute__((ext_vector_type(16))) float    fx16;

// ---------------------------------------------------------------------------
// Prep
// ---------------------------------------------------------------------------
__global__ __launch_bounds__(256) void tr512(
    const float* __restrict__ W2, float* __restrict__ W2T)
{
    __shared__ float t[32][33];
    const int bx = blockIdx.x & 15, by = blockIdx.x >> 4;
    const int x = threadIdx.x & 31, y8 = threadIdx.x >> 5;
#pragma unroll
    for (int r = 0; r < 32; r += 8)
        t[r + y8][x] = W2[(size_t)(by * 32 + r + y8) * 512 + bx * 32 + x];
    __syncthreads();
#pragma unroll
    for (int r = 0; r < 32; r += 8)
        W2T[(size_t)(bx * 32 + r + y8) * 512 + by * 32 + x] = t[x][r + y8];
}

__global__ __launch_bounds__(256) void wc32(
    const float* __restrict__ W2T, const float* __restrict__ W1,
    float* __restrict__ Wc)
{
    __shared__ float As[16][32];
    __shared__ float Bs[16][32];
    const int tid = threadIdx.x;
    const int ty = tid >> 3, tx = tid & 7;
    const int m0 = blockIdx.y * 32, n0 = blockIdx.x * 32;
    float acc[4] = {0.f, 0.f, 0.f, 0.f};

    for (int k0 = 0; k0 < 512; k0 += 16) {
#pragma unroll
        for (int t = 0; t < 2; ++t) {
            const int idx = tid + t * 256;
            const int r = idx >> 5, c = idx & 31;
            As[r][c] = W2T[(size_t)(k0 + r) * 512 + m0 + c];
            const int n = n0 + c;
            Bs[r][c] = (n < 720) ? W1[(size_t)(k0 + r) * 720 + n] : 0.f;
        }
        __syncthreads();
#pragma unroll
        for (int kk = 0; kk < 16; ++kk) {
            const float a = As[kk][ty];
#pragma unroll
            for (int j = 0; j < 4; ++j)
                acc[j] = fmaf(a, Bs[kk][tx * 4 + j], acc[j]);
        }
        __syncthreads();
    }
    const int m = m0 + ty;
#pragma unroll
    for (int j = 0; j < 4; ++j) {
        const int n = n0 + tx * 4 + j;
        if (n < 720) Wc[(size_t)m * 720 + n] = acc[j];
    }
}

__global__ __launch_bounds__(256) void bc_k(
    const float* __restrict__ W2, const float* __restrict__ b1,
    const float* __restrict__ b2, float* __restrict__ bc)
{
    const int m = blockIdx.x * 256 + threadIdx.x;
    if (m >= 512) return;
    float a = b2[m];
    for (int h = 0; h < 512; ++h) a += W2[m * 512 + h] * b1[h];
    bc[m] = a;
}

// 32x32x16 A-frags, K permuted (kp = tap*80+ci), 720 = 45*16 exactly.
__global__ __launch_bounds__(256) void swz_wc2(
    const float* __restrict__ Wc, f16* __restrict__ Wcsw2)
{
    const int idx = blockIdx.x * 256 + threadIdx.x;
    if (idx >= 45 * 16 * 64) return;
    const int lane = idx & 63;
    const int t = idx >> 6;
    const int mtg = t & 15, ks = t >> 4;
    const int m = mtg * 32 + (lane & 31);
    const int k0 = ks * 16 + (lane >> 5) * 8;
    h8_t v;
#pragma unroll
    for (int j = 0; j < 8; ++j) {
        const int kp = k0 + j;
        const int tap = kp / 80, ci = kp - tap * 80;
        v[j] = (f16)Wc[(size_t)m * 720 + ci * 9 + tap];
    }
    *(h8_t*)(Wcsw2 + (size_t)idx * 8) = v;
}

// 32x32x16 A-frags for W3 (80x512 padded to 96 rows).
__global__ __launch_bounds__(256) void swz_w32(
    const float* __restrict__ W3, f16* __restrict__ W3sw2)
{
    const int idx = blockIdx.x * 256 + threadIdx.x;
    if (idx >= 32 * 3 * 64) return;
    const int lane = idx & 63;
    const int t = idx >> 6;
    const int mt = t % 3, ks2 = t / 3;
    const int m = mt * 32 + (lane & 31);
    const int k0 = ks2 * 16 + (lane >> 5) * 8;
    h8_t v;
#pragma unroll
    for (int j = 0; j < 8; ++j)
        v[j] = (f16)((m < 80) ? W3[(size_t)m * 512 + k0 + j] : 0.f);
    *(h8_t*)(W3sw2 + (size_t)idx * 8) = v;
}

// Seed state + Aseed init (merged).
__global__ __launch_bounds__(256) void seed_k(
    const float* __restrict__ z, const float* __restrict__ b3,
    float* __restrict__ Sf32, f16* __restrict__ Smf16,
    float* __restrict__ Aseed)
{
    const int idx = blockIdx.x * 256 + threadIdx.x;
    if (idx < NPIX)
        Aseed[idx] = b3[0] + (((idx & 1023) == 528) ? 1.f : 0.f);
    if (idx >= 640) return;
    const int b = idx / 80, c = idx - b * 80;
    const int n = b * 1024 + 16 * 32 + 16;
    const float v = (c == 0) ? 1.f : z[b * 100 + (c - 1)];
    Sf32[(size_t)c * NPIX + n] = v;
    Smf16[(size_t)n * 80 + c] = (f16)v;
}

// ---------------------------------------------------------------------------
// K1: H = relu(Wc * im2col(S)) + alpha-dot accumulation.
// grid (32, 8), 512 threads: x = 8-row band (img b = pb>>2, rows y0..y0+7,
// y0 = (pb&3)*8), y = mb (64-channel chunk). Wave w (0..7) = row y0+w.
// 256 blocks x 8 waves = 16 waves/CU. msT = 10-row window (54.4 KB).
// A-frag prefetch ring depth 8; staging two-phase (loads hoisted).
// ---------------------------------------------------------------------------
__global__ __launch_bounds__(512) void k1_gemmH(
    const f16* __restrict__ Smf16, const f16* __restrict__ Wcsw2,
    const float* __restrict__ bc, const float* __restrict__ W3,
    f16* __restrict__ H, float* __restrict__ Aseed)
{
    __shared__ f16  msT[27200];     // 10 octets x (10 rows x 34 px) x 8 halfs
    __shared__ float bcL[64];
    __shared__ float waL[64];

    const int tid = threadIdx.x;
    const int lane = tid & 63, w = tid >> 6;     // w in 0..7
    const int li = lane & 31, q2 = lane >> 5;
    const int pb = blockIdx.x, mb = blockIdx.y;
    const int b = pb >> 2, y0 = (pb & 3) * 8;
    const int gb = b * 1024;

    if (tid < 64) {
        bcL[tid] = bc[mb * 64 + tid];
        waL[tid] = W3[mb * 64 + tid];      // W3 row 0
    }
    // staging phase 1: hoisted global loads (pixel-major fp16, 16B each)
    h8_t sv[7];
#pragma unroll
    for (int t = 0; t < 7; ++t) {
        const int idx = tid + t * 512;
        if (idx < 3400) {
            const int p = idx / 10, cc = idx - p * 10;
            const int r = p / 34, xi = p - r * 34;
            const int gx = xi - 1, y = y0 - 1 + r;
            if (((unsigned)y < 32u) & ((unsigned)gx < 32u)) {
                sv[t] = *(const h8_t*)(Smf16 +
                         (size_t)(gb + y * 32 + gx) * 80 + cc * 8);
            } else {
#pragma unroll
                for (int j = 0; j < 8; ++j) sv[t][j] = (f16)0.f;
            }
        }
    }
    // staging phase 2: LDS stores
#pragma unroll
    for (int t = 0; t < 7; ++t) {
        const int idx = tid + t * 512;
        if (idx < 3400) {
            const int p = idx / 10, cc = idx - p * 10;
            *(h8_t*)(msT + (size_t)(cc * 340 + p) * 8) = sv[t];
        }
    }
    __syncthreads();

    int pxh[9];
#pragma unroll
    for (int t = 0; t < 9; ++t)
        pxh[t] = ((t / 3) * 34 + li + (t % 3)) * 8;
    const int wbase = w * 272;      // wave's row base: w * 34 * 8

    fx16 acc[2];
#pragma unroll
    for (int i = 0; i < 2; ++i)
#pragma unroll
        for (int r = 0; r < 16; ++r) acc[i][r] = 0.f;

    h8_t abuf[8][2];                // depth-8 prefetch ring
#pragma unroll
    for (int pk = 0; pk < 8; ++pk)
#pragma unroll
        for (int i = 0; i < 2; ++i)
            abuf[pk][i] = *(const h8_t*)(Wcsw2 +
                (((size_t)pk * 16 + (mb * 2 + i)) * 64 + lane) * 8);

#pragma unroll
    for (int ks = 0; ks < 45; ++ks) {
        const int o0 = 2 * ks, o1 = 2 * ks + 1;
        const int a0 = (o0 % 10) * 2720 + wbase + pxh[o0 / 10];
        const int a1 = (o1 % 10) * 2720 + wbase + pxh[o1 / 10];
        const h8_t bf = *(const h8_t*)(msT + (q2 ? a1 : a0));
        h8_t av[2];
#pragma unroll
        for (int i = 0; i < 2; ++i) av[i] = abuf[ks & 7][i];
        if (ks + 8 < 45) {
#pragma unroll
            for (int i = 0; i < 2; ++i)
                abuf[ks & 7][i] = *(const h8_t*)(Wcsw2 +
                    (((size_t)(ks + 8) * 16 + (mb * 2 + i)) * 64 + lane) * 8);
        }
#pragma unroll
        for (int i = 0; i < 2; ++i)
            acc[i] = __builtin_amdgcn_mfma_f32_32x32x16_f16(
                av[i], bf, acc[i], 0, 0, 0);
    }

    // epilogue: relu(acc + bc) -> H octet layout; alpha partial dot
    const size_t px = (size_t)(gb + (y0 + w) * 32 + li);
    float pd = 0.f;
#pragma unroll
    for (int i = 0; i < 2; ++i) {
#pragma unroll
        for (int aa = 0; aa < 4; ++aa) {
            const int chl = i * 32 + 8 * aa + 4 * q2;
            const int co = mb * 8 + i * 4 + aa;
            h4_t v4;
#pragma unroll
            for (int rb = 0; rb < 4; ++rb) {
                const float hv = fmaxf(acc[i][aa * 4 + rb] + bcL[chl + rb], 0.f);
                v4[rb] = (f16)hv;
                pd = fmaf(hv, waL[chl + rb], pd);
            }
            *(h4_t*)(H + ((size_t)co * NPIX + px) * 8 + 4 * q2) = v4;
        }
    }
    // combine lane (q2=0) with lane+32 (q2=1) partials, one atomic per px
    const float pd2 = __shfl_down(pd, 32);
    if (lane < 32) atomicAdd(&Aseed[px], pd + pd2);
}

// ---------------------------------------------------------------------------
// K2: upd = W3*H (own row only); live mask from Aseed (alphaN) + Sold ch0
// (alphaO); writes Snew / Smf16 / AseedNext. grid 256: b = blk>>5, y = blk&31.
// W3 A-frags and H B-frags hoisted into registers before the MFMA chain.
// ---------------------------------------------------------------------------
__global__ __launch_bounds__(256) void k2_update(
    const f16* __restrict__ H, const f16* __restrict__ W3sw2,
    const float* __restrict__ b3,
    const float* __restrict__ Sold, float* __restrict__ Snew,
    f16* __restrict__ Smf16,
    const float* __restrict__ AseedC, float* __restrict__ AseedN)
{
    __shared__ float redT[12288];    // ((w*3+mt)*4+aa)*256 + lane*4, 48 KB
    __shared__ float alphaO3[96];
    __shared__ float alphaN3[96];
    __shared__ float b3L[80];
    __shared__ float livef[32];

    const int tid = threadIdx.x;
    const int lane = tid & 63, w = tid >> 6;
    const int li = lane & 31, q2 = lane >> 5;
    const int blk = blockIdx.x;
    const int b = blk >> 5, y = blk & 31;
    const int gb = b * 1024;
    const size_t px = (size_t)(gb + y * 32 + li);

    // hoisted fragment loads: 8 H B-frags + 24 W3 A-frags, all issued early
    h8_t hb[8], w3r[8][3];
#pragma unroll
    for (int k2 = 0; k2 < 8; ++k2) {
        const int ks2 = w * 8 + k2;
        hb[k2] = *(const h8_t*)(H + ((size_t)(ks2 * 2 + q2) * NPIX + px) * 8);
#pragma unroll
        for (int mt = 0; mt < 3; ++mt)
            w3r[k2][mt] = *(const h8_t*)(W3sw2 +
                (((size_t)ks2 * 3 + mt) * 64 + lane) * 8);
    }

    if (tid < 80) b3L[tid] = b3[tid];
    if (tid < 96) {
        const int r = tid >> 5, x = tid & 31, yy = y - 1 + r;
        const bool inb = (unsigned)yy < 32u;
        alphaO3[tid] = inb ? Sold[gb + yy * 32 + x]   : -1e30f;
        alphaN3[tid] = inb ? AseedC[gb + yy * 32 + x] : -1e30f;
    }

    fx16 acc3[3];
#pragma unroll
    for (int mt = 0; mt < 3; ++mt)
#pragma unroll
        for (int r = 0; r < 16; ++r) acc3[mt][r] = 0.f;
#pragma unroll
    for (int k2 = 0; k2 < 8; ++k2) {
#pragma unroll
        for (int mt = 0; mt < 3; ++mt)
            acc3[mt] = __builtin_amdgcn_mfma_f32_32x32x16_f16(
                w3r[k2][mt], hb[k2], acc3[mt], 0, 0, 0);
    }

    // stash partials
#pragma unroll
    for (int mt = 0; mt < 3; ++mt)
#pragma unroll
        for (int aa = 0; aa < 4; ++aa) {
            float4 v;
            v.x = acc3[mt][aa * 4 + 0]; v.y = acc3[mt][aa * 4 + 1];
            v.z = acc3[mt][aa * 4 + 2]; v.w = acc3[mt][aa * 4 + 3];
            *(float4*)(redT + (((w * 3 + mt) * 4 + aa) * 256 + lane * 4)) = v;
        }
    __syncthreads();

    // live mask for own row (3x3 window over alphaN/alphaO)
    if (tid < 32) {
        float mN = -1e30f, mO = -1e30f;
#pragma unroll
        for (int r = 0; r < 3; ++r)
#pragma unroll
            for (int dx = -1; dx <= 1; ++dx) {
                const int xx = tid + dx;
                if ((unsigned)xx < 32u) {
                    mN = fmaxf(mN, alphaN3[r * 32 + xx]);
                    mO = fmaxf(mO, alphaO3[r * 32 + xx]);
                }
            }
        livef[tid] = (mN > T_ALIVE && mO > T_ALIVE) ? 1.f : 0.f;
    }
    __syncthreads();

    // epilogue: waves 0..2 reduce + write Snew / Smf16 / AseedN
    if (w < 3) {
        const int mt = w;
        const float lv = livef[li];
#pragma unroll
        for (int aa = 0; aa < 4; ++aa) {
            const float4 s0 = *(float4*)(redT + (((0 * 3 + mt) * 4 + aa) * 256 + lane * 4));
            const float4 s1 = *(float4*)(redT + (((1 * 3 + mt) * 4 + aa) * 256 + lane * 4));
            const float4 s2 = *(float4*)(redT + (((2 * 3 + mt) * 4 + aa) * 256 + lane * 4));
            const float4 s3 = *(float4*)(redT + (((3 * 3 + mt) * 4 + aa) * 256 + lane * 4));
            const float t4[4] = {s0.x + s1.x + s2.x + s3.x,
                                 s0.y + s1.y + s2.y + s3.y,
                                 s0.z + s1.z + s2.z + s3.z,
                                 s0.w + s1.w + s2.w + s3.w};
            const int ch0 = mt * 32 + 8 * aa + 4 * q2;
            if (ch0 + 3 < 80) {
                h4_t v4;
                float vrb0 = 0.f;
#pragma unroll
                for (int rb = 0; rb < 4; ++rb) {
                    const int ch = ch0 + rb;
                    const size_t idx = (size_t)ch * NPIX + px;
                    const float v = (Sold[idx] + t4[rb] + b3L[ch]) * lv;
                    Snew[idx] = v;
                    v4[rb] = (f16)v;
                    if (rb == 0) vrb0 = v;
                }
                *(h4_t*)(Smf16 + px * 80 + ch0) = v4;
                // seed next step's alpha accumulator with Snew_ch0 + b3[0]
                if (mt == 0 && aa == 0 && q2 == 0)
                    AseedN[px] = vrb0 + b3L[0];
            }
        }
    }
}

// ---------------------------------------------------------------------------
extern "C" void kernel_launch(void* const* d_in, const int* in_sizes, int n_in,
                              void* d_out, int out_size, void* d_ws, size_t ws_size,
                              hipStream_t stream)
{
    const float* z  = (const float*)d_in[0];
    const float* W1 = (const float*)d_in[1];   // 512 x 720
    const float* b1 = (const float*)d_in[2];
    const float* W2 = (const float*)d_in[3];   // 512 x 512
    const float* b2 = (const float*)d_in[4];
    const float* W3 = (const float*)d_in[5];   // 80 x 512
    const float* b3 = (const float*)d_in[6];

    char* ws = (char*)d_ws;
    float* S0    = (float*)ws;  ws += (size_t)80 * NPIX * 4;
    float* S1    = (float*)ws;  ws += (size_t)80 * NPIX * 4;
    f16*   Sm0   = (f16*)ws;   ws += (size_t)NPIX * 80 * 2;
    f16*   Sm1   = (f16*)ws;   ws += (size_t)NPIX * 80 * 2;
    float* As0   = (float*)ws;  ws += NPIX * 4;
    float* As1   = (float*)ws;  ws += NPIX * 4;
    float* bc    = (float*)ws;  ws += 512 * 4;
    float* Wc    = (float*)ws;  ws += (size_t)512 * 720 * 4;
    float* W2T   = (float*)ws;  ws += (size_t)512 * 512 * 4;
    f16*   Wcsw2 = (f16*)ws;   ws += (size_t)45 * 16 * 64 * 8 * 2;
    f16*   W3sw2 = (f16*)ws;   ws += (size_t)32 * 3 * 64 * 8 * 2;
    f16*   H     = (f16*)ws;   ws += (size_t)64 * NPIX * 8 * 2;    // 8 MB

    hipMemsetAsync(S0, 0, (size_t)80 * NPIX * 4, stream);
    hipMemsetAsync(Sm0, 0, (size_t)NPIX * 80 * 2, stream);
    seed_k<<<32, 256, 0, stream>>>(z, b3, S0, Sm0, As0);
    tr512<<<256, 256, 0, stream>>>(W2, W2T);
    wc32<<<dim3(23, 16), 256, 0, stream>>>(W2T, W1, Wc);
    bc_k<<<2, 256, 0, stream>>>(W2, b1, b2, bc);
    swz_wc2<<<180, 256, 0, stream>>>(Wc, Wcsw2);
    swz_w32<<<24, 256, 0, stream>>>(W3, W3sw2);

    float* Scur = S0;  float* Snxt = S1;
    f16*   Mcur = Sm0; f16*   Mnxt = Sm1;
    for (int s = 0; s < 64; ++s) {
        float* AsC = (s & 1) ? As1 : As0;
        float* AsN = (s & 1) ? As0 : As1;
        k1_gemmH<<<dim3(32, 8), 512, 0, stream>>>(Mcur, Wcsw2, bc, W3, H, AsC);
        k2_update<<<256, 256, 0, stream>>>(H, W3sw2, b3, Scur, Snxt, Mnxt,
                                           AsC, AsN);
        float* t = Scur; Scur = Snxt; Snxt = t;
        f16*   m = Mcur; Mcur = Mnxt; Mnxt = m;
    }

    // output = masked alpha plane = first 8192 floats of final state
    hipMemcpyAsync(d_out, Scur, NPIX * sizeof(float),
                   hipMemcpyDeviceToDevice, stream);
}

// Round 15
// 1147.297 us; speedup vs baseline: 1.2757x; 1.2757x over previous
//
#include <hip/hip_runtime.h>

// CAGenerator: 64-step neural CA — 2 dispatches/step, fence-free.
// R15: H never leaves the CU. kA (256 blocks x 512 thr, 1 pixel-row each):
//   phase 1: 8 waves compute all 512 H channels for the row (64 ch/wave),
//            im2col on the fly from a 3-row masked-state LDS window
//            (permuted-K kp = tap*80+ci, B-frag = one ds_read_b128);
//            H -> LDS (32 KB, octet layout).
//   phase 2: waves 0-2 do upd = W3*H FULL-K in-block (no atomics/reduce),
//            write U = S + upd + b3 (unmasked, ch-major fp32).
// kB (256 blocks x 256 thr): live mask from U ch0 (alphaN) and S ch0
//   (alphaO), Snew = U*live -> Sf32' + Smf16' (px-major fp16); last step
//   also writes dout. No H global buffer, no Aseed, no final memcpy.
// Folded: Wc = W2@W1 (512x720), bc = W2@b1+b2. mask=uniform()<1.0 -> no RNG.

#define NPIX 8192
#define T_ALIVE 0.01f

typedef _Float16 f16;
typedef __attribute__((ext_vector_type(8)))  _Float16 h8_t;
typedef __attribute__((ext_vector_type(4)))  _Float16 h4_t;
typedef __attribute__((ext_vector_type(16))) float    fx16;

// ---------------------------------------------------------------------------
// Prep (unchanged from R13)
// ---------------------------------------------------------------------------
__global__ __launch_bounds__(256) void tr512(
    const float* __restrict__ W2, float* __restrict__ W2T)
{
    __shared__ float t[32][33];
    const int bx = blockIdx.x & 15, by = blockIdx.x >> 4;
    const int x = threadIdx.x & 31, y8 = threadIdx.x >> 5;
#pragma unroll
    for (int r = 0; r < 32; r += 8)
        t[r + y8][x] = W2[(size_t)(by * 32 + r + y8) * 512 + bx * 32 + x];
    __syncthreads();
#pragma unroll
    for (int r = 0; r < 32; r += 8)
        W2T[(size_t)(bx * 32 + r + y8) * 512 + by * 32 + x] = t[x][r + y8];
}

__global__ __launch_bounds__(256) void wc32(
    const float* __restrict__ W2T, const float* __restrict__ W1,
    float* __restrict__ Wc)
{
    __shared__ float As[16][32];
    __shared__ float Bs[16][32];
    const int tid = threadIdx.x;
    const int ty = tid >> 3, tx = tid & 7;
    const int m0 = blockIdx.y * 32, n0 = blockIdx.x * 32;
    float acc[4] = {0.f, 0.f, 0.f, 0.f};

    for (int k0 = 0; k0 < 512; k0 += 16) {
#pragma unroll
        for (int t = 0; t < 2; ++t) {
            const int idx = tid + t * 256;
            const int r = idx >> 5, c = idx & 31;
            As[r][c] = W2T[(size_t)(k0 + r) * 512 + m0 + c];
            const int n = n0 + c;
            Bs[r][c] = (n < 720) ? W1[(size_t)(k0 + r) * 720 + n] : 0.f;
        }
        __syncthreads();
#pragma unroll
        for (int kk = 0; kk < 16; ++kk) {
            const float a = As[kk][ty];
#pragma unroll
            for (int j = 0; j < 4; ++j)
                acc[j] = fmaf(a, Bs[kk][tx * 4 + j], acc[j]);
        }
        __syncthreads();
    }
    const int m = m0 + ty;
#pragma unroll
    for (int j = 0; j < 4; ++j) {
        const int n = n0 + tx * 4 + j;
        if (n < 720) Wc[(size_t)m * 720 + n] = acc[j];
    }
}

__global__ __launch_bounds__(256) void bc_k(
    const float* __restrict__ W2, const float* __restrict__ b1,
    const float* __restrict__ b2, float* __restrict__ bc)
{
    const int m = blockIdx.x * 256 + threadIdx.x;
    if (m >= 512) return;
    float a = b2[m];
    for (int h = 0; h < 512; ++h) a += W2[m * 512 + h] * b1[h];
    bc[m] = a;
}

// 32x32x16 A-frags, K permuted (kp = tap*80+ci), 720 = 45*16 exactly.
__global__ __launch_bounds__(256) void swz_wc2(
    const float* __restrict__ Wc, f16* __restrict__ Wcsw2)
{
    const int idx = blockIdx.x * 256 + threadIdx.x;
    if (idx >= 45 * 16 * 64) return;
    const int lane = idx & 63;
    const int t = idx >> 6;
    const int mtg = t & 15, ks = t >> 4;
    const int m = mtg * 32 + (lane & 31);
    const int k0 = ks * 16 + (lane >> 5) * 8;
    h8_t v;
#pragma unroll
    for (int j = 0; j < 8; ++j) {
        const int kp = k0 + j;
        const int tap = kp / 80, ci = kp - tap * 80;
        v[j] = (f16)Wc[(size_t)m * 720 + ci * 9 + tap];
    }
    *(h8_t*)(Wcsw2 + (size_t)idx * 8) = v;
}

// 32x32x16 A-frags for W3 (80x512 padded to 96 rows).
__global__ __launch_bounds__(256) void swz_w32(
    const float* __restrict__ W3, f16* __restrict__ W3sw2)
{
    const int idx = blockIdx.x * 256 + threadIdx.x;
    if (idx >= 32 * 3 * 64) return;
    const int lane = idx & 63;
    const int t = idx >> 6;
    const int mt = t % 3, ks2 = t / 3;
    const int m = mt * 32 + (lane & 31);
    const int k0 = ks2 * 16 + (lane >> 5) * 8;
    h8_t v;
#pragma unroll
    for (int j = 0; j < 8; ++j)
        v[j] = (f16)((m < 80) ? W3[(size_t)m * 512 + k0 + j] : 0.f);
    *(h8_t*)(W3sw2 + (size_t)idx * 8) = v;
}

__global__ __launch_bounds__(256) void seed_k(
    const float* __restrict__ z, float* __restrict__ Sf32,
    f16* __restrict__ Smf16)
{
    const int idx = blockIdx.x * 256 + threadIdx.x;
    if (idx >= 640) return;
    const int b = idx / 80, c = idx - b * 80;
    const int n = b * 1024 + 16 * 32 + 16;
    const float v = (c == 0) ? 1.f : z[b * 100 + (c - 1)];
    Sf32[(size_t)c * NPIX + n] = v;
    Smf16[(size_t)n * 80 + c] = (f16)v;
}

// ---------------------------------------------------------------------------
// kA: all 512 H for one pixel row in-block; gemm3 full-K in-block; writes U.
// grid 256, 512 threads: b = blk>>5, y = blk&31. Wave w (0..7) = 64-ch chunk.
// ---------------------------------------------------------------------------
__global__ __launch_bounds__(512) void kA(
    const f16* __restrict__ Smf16, const f16* __restrict__ Wcsw2,
    const float* __restrict__ bc, const f16* __restrict__ W3sw2,
    const float* __restrict__ b3,
    const float* __restrict__ Sold, float* __restrict__ U)
{
    __shared__ f16   msT[8160];     // 10 cc x (3 rows x 34 px) x 8 halfs
    __shared__ f16   Hsw[16384];    // 64 co x 32 px x 8 halfs = 32 KB
    __shared__ float bcL[512];
    __shared__ float b3L[80];

    const int tid = threadIdx.x;
    const int lane = tid & 63, w = tid >> 6;     // w = 0..7 (chunk)
    const int li = lane & 31, q2 = lane >> 5;
    const int blk = blockIdx.x;
    const int b = blk >> 5, y = blk & 31;
    const int gb = b * 1024;

    if (tid < 512) bcL[tid] = bc[tid];
    if (tid < 80)  b3L[tid] = b3[tid];

    // stage masked state (rows y-1..y+1), pixel-major fp16 octets
    for (int idx = tid; idx < 1020; idx += 512) {
        const int p = idx / 10, cc = idx - p * 10;
        const int r = p / 34, xi = p - r * 34;
        const int gx = xi - 1, yy = y - 1 + r;
        h8_t v;
        if (((unsigned)yy < 32u) & ((unsigned)gx < 32u)) {
            v = *(const h8_t*)(Smf16 + (size_t)(gb + yy * 32 + gx) * 80 + cc * 8);
        } else {
#pragma unroll
            for (int j = 0; j < 8; ++j) v[j] = (f16)0.f;
        }
        *(h8_t*)(msT + (size_t)(cc * 102 + p) * 8) = v;
    }
    __syncthreads();

    // ---------------- phase 1: H chunk (64 ch x 32 px) per wave -----------
    int pxh[9];
#pragma unroll
    for (int t = 0; t < 9; ++t)
        pxh[t] = ((t / 3) * 34 + li + (t % 3)) * 8;

    fx16 acc[2];
#pragma unroll
    for (int i = 0; i < 2; ++i)
#pragma unroll
        for (int r = 0; r < 16; ++r) acc[i][r] = 0.f;

    h8_t abuf[8][2];                // depth-8 prefetch ring
#pragma unroll
    for (int pk = 0; pk < 8; ++pk)
#pragma unroll
        for (int i = 0; i < 2; ++i)
            abuf[pk][i] = *(const h8_t*)(Wcsw2 +
                (((size_t)pk * 16 + (w * 2 + i)) * 64 + lane) * 8);

#pragma unroll
    for (int ks = 0; ks < 45; ++ks) {
        const int o0 = 2 * ks, o1 = 2 * ks + 1;
        const int a0 = (o0 % 10) * 816 + pxh[o0 / 10];
        const int a1 = (o1 % 10) * 816 + pxh[o1 / 10];
        const h8_t bf = *(const h8_t*)(msT + (q2 ? a1 : a0));
        h8_t av[2];
#pragma unroll
        for (int i = 0; i < 2; ++i) av[i] = abuf[ks & 7][i];
        if (ks + 8 < 45) {
#pragma unroll
            for (int i = 0; i < 2; ++i)
                abuf[ks & 7][i] = *(const h8_t*)(Wcsw2 +
                    (((size_t)(ks + 8) * 16 + (w * 2 + i)) * 64 + lane) * 8);
        }
#pragma unroll
        for (int i = 0; i < 2; ++i)
            acc[i] = __builtin_amdgcn_mfma_f32_32x32x16_f16(
                av[i], bf, acc[i], 0, 0, 0);
    }

    // relu(acc + bc) -> Hsw octet layout (octet co holds channels 8co..8co+7)
#pragma unroll
    for (int i = 0; i < 2; ++i) {
#pragma unroll
        for (int aa = 0; aa < 4; ++aa) {
            const int chl = i * 32 + 8 * aa + 4 * q2;
            const int co = w * 8 + i * 4 + aa;
            h4_t v4;
#pragma unroll
            for (int rb = 0; rb < 4; ++rb)
                v4[rb] = (f16)fmaxf(acc[i][aa * 4 + rb] + bcL[w * 64 + chl + rb], 0.f);
            *(h4_t*)(Hsw + ((size_t)co * 32 + li) * 8 + 4 * q2) = v4;
        }
    }
    __syncthreads();

    // ---------------- phase 2: upd = W3*H full-K (waves 0..2) -------------
    if (w < 3) {
        const int mt = w;
        h8_t ar[8];
#pragma unroll
        for (int pk = 0; pk < 8; ++pk)
            ar[pk] = *(const h8_t*)(W3sw2 +
                (((size_t)pk * 3 + mt) * 64 + lane) * 8);

        fx16 acc3;
#pragma unroll
        for (int r = 0; r < 16; ++r) acc3[r] = 0.f;
#pragma unroll
        for (int ks2 = 0; ks2 < 32; ++ks2) {
            const h8_t bf = *(const h8_t*)(Hsw +
                ((size_t)(ks2 * 2 + q2) * 32 + li) * 8);
            const h8_t a = ar[ks2 & 7];
            if (ks2 + 8 < 32)
                ar[ks2 & 7] = *(const h8_t*)(W3sw2 +
                    (((size_t)(ks2 + 8) * 3 + mt) * 64 + lane) * 8);
            acc3 = __builtin_amdgcn_mfma_f32_32x32x16_f16(a, bf, acc3, 0, 0, 0);
        }

        // U = Sold + upd + b3 (unmasked)
        const size_t px = (size_t)(gb + y * 32 + li);
#pragma unroll
        for (int aa = 0; aa < 4; ++aa)
#pragma unroll
            for (int rb = 0; rb < 4; ++rb) {
                const int ch = mt * 32 + rb + 8 * aa + 4 * q2;
                if (ch < 80) {
                    const size_t idx = (size_t)ch * NPIX + px;
                    U[idx] = Sold[idx] + acc3[aa * 4 + rb] + b3L[ch];
                }
            }
    }
}

// ---------------------------------------------------------------------------
// kB: live mask + state write. grid 256: b = blk>>5, y = blk&31.
// alphaO = Sold ch0 (masked), alphaN = U ch0. Snew = U*live (both layouts).
// On last step also writes dout = Snew ch0.
// ---------------------------------------------------------------------------
__global__ __launch_bounds__(256) void kB(
    const float* __restrict__ U, const float* __restrict__ Sold,
    float* __restrict__ Snew, f16* __restrict__ Smf16,
    float* __restrict__ dout, int last)
{
    __shared__ float alphaO3[96];
    __shared__ float alphaN3[96];
    __shared__ float livef[32];

    const int tid = threadIdx.x;
    const int blk = blockIdx.x;
    const int b = blk >> 5, y = blk & 31;
    const int gb = b * 1024;
    const int base = gb + y * 32;

    if (tid < 96) {
        const int r = tid >> 5, x = tid & 31, yy = y - 1 + r;
        if ((unsigned)yy < 32u) {
            alphaO3[tid] = Sold[gb + yy * 32 + x];
            alphaN3[tid] = U[gb + yy * 32 + x];
        } else {
            alphaO3[tid] = -1e30f;
            alphaN3[tid] = -1e30f;
        }
    }
    __syncthreads();

    if (tid < 32) {
        float mN = -1e30f, mO = -1e30f;
#pragma unroll
        for (int r = 0; r < 3; ++r)
#pragma unroll
            for (int dx = -1; dx <= 1; ++dx) {
                const int xx = tid + dx;
                if ((unsigned)xx < 32u) {
                    mN = fmaxf(mN, alphaN3[r * 32 + xx]);
                    mO = fmaxf(mO, alphaO3[r * 32 + xx]);
                }
            }
        livef[tid] = (mN > T_ALIVE && mO > T_ALIVE) ? 1.f : 0.f;
    }
    __syncthreads();

    // 80 ch x 32 px in channel-quads
    for (int q = tid; q < 640; q += 256) {
        const int cq = q >> 5, x = q & 31;
        const float lv = livef[x];
        const size_t pxg = (size_t)(base + x);
        h4_t v4;
        float v0 = 0.f;
#pragma unroll
        for (int rb = 0; rb < 4; ++rb) {
            const int ch = cq * 4 + rb;
            const size_t idx = (size_t)ch * NPIX + pxg;
            const float v = U[idx] * lv;
            Snew[idx] = v;
            v4[rb] = (f16)v;
            if (rb == 0) v0 = v;
        }
        *(h4_t*)(Smf16 + pxg * 80 + cq * 4) = v4;
        if (last && cq == 0) dout[pxg] = v0;
    }
}

// ---------------------------------------------------------------------------
extern "C" void kernel_launch(void* const* d_in, const int* in_sizes, int n_in,
                              void* d_out, int out_size, void* d_ws, size_t ws_size,
                              hipStream_t stream)
{
    const float* z  = (const float*)d_in[0];
    const float* W1 = (const float*)d_in[1];   // 512 x 720
    const float* b1 = (const float*)d_in[2];
    const float* W2 = (const float*)d_in[3];   // 512 x 512
    const float* b2 = (const float*)d_in[4];
    const float* W3 = (const float*)d_in[5];   // 80 x 512
    const float* b3 = (const float*)d_in[6];

    char* ws = (char*)d_ws;
    float* S0    = (float*)ws;  ws += (size_t)80 * NPIX * 4;
    float* S1    = (float*)ws;  ws += (size_t)80 * NPIX * 4;
    f16*   Sm0   = (f16*)ws;   ws += (size_t)NPIX * 80 * 2;
    f16*   Sm1   = (f16*)ws;   ws += (size_t)NPIX * 80 * 2;
    float* Ubuf  = (float*)ws;  ws += (size_t)80 * NPIX * 4;
    float* bc    = (float*)ws;  ws += 512 * 4;
    float* Wc    = (float*)ws;  ws += (size_t)512 * 720 * 4;
    float* W2T   = (float*)ws;  ws += (size_t)512 * 512 * 4;
    f16*   Wcsw2 = (f16*)ws;   ws += (size_t)45 * 16 * 64 * 8 * 2;
    f16*   W3sw2 = (f16*)ws;   ws += (size_t)32 * 3 * 64 * 8 * 2;

    hipMemsetAsync(S0, 0, (size_t)80 * NPIX * 4, stream);
    hipMemsetAsync(Sm0, 0, (size_t)NPIX * 80 * 2, stream);
    seed_k<<<3, 256, 0, stream>>>(z, S0, Sm0);
    tr512<<<256, 256, 0, stream>>>(W2, W2T);
    wc32<<<dim3(23, 16), 256, 0, stream>>>(W2T, W1, Wc);
    bc_k<<<2, 256, 0, stream>>>(W2, b1, b2, bc);
    swz_wc2<<<180, 256, 0, stream>>>(Wc, Wcsw2);
    swz_w32<<<24, 256, 0, stream>>>(W3, W3sw2);

    float* Scur = S0;  float* Snxt = S1;
    f16*   Mcur = Sm0; f16*   Mnxt = Sm1;
    for (int s = 0; s < 64; ++s) {
        kA<<<256, 512, 0, stream>>>(Mcur, Wcsw2, bc, W3sw2, b3, Scur, Ubuf);
        kB<<<256, 256, 0, stream>>>(Ubuf, Scur, Snxt, Mnxt,
                                    (float*)d_out, (s == 63) ? 1 : 0);
        float* t = Scur; Scur = Snxt; Snxt = t;
        f16*   m = Mcur; Mcur = Mnxt; Mnxt = m;
    }
}